// Round 6
// baseline (45.377 us; speedup 1.0000x reference)
//
#include <hip/hip_runtime.h>
#include <hip/hip_cooperative_groups.h>
#include <cmath>

namespace cg = cooperative_groups;

// Problem constants: B=4, L=8192, H=128, P=64
constexpr int Bn = 4;
constexpr int Ln = 8192;
constexpr int Hn = 128;
constexpr int Pn = 64;
constexpr int Kn = 128;         // 2*P interleaved (k = 2p+c)
constexpr int Sc = 64;          // chunk length (rows per block)
constexpr int NC = Ln / Sc;     // 128 chunks per batch
constexpr int NBLK = Bn * NC;   // 512 blocks

typedef float f4 __attribute__((ext_vector_type(4)));
typedef float f32x4 __attribute__((ext_vector_type(4)));
typedef unsigned short us8 __attribute__((ext_vector_type(8)));
typedef unsigned short us4 __attribute__((ext_vector_type(4)));
typedef __bf16 bf16x8 __attribute__((ext_vector_type(8)));

__device__ __forceinline__ unsigned short f2bf(float f) {
  unsigned u = __builtin_bit_cast(unsigned, f);
  u += 0x7fffu + ((u >> 16) & 1u);        // round-to-nearest-even
  return (unsigned short)(u >> 16);
}

__device__ __forceinline__ f32x4 mfma_bf16(us8 a, us8 b, f32x4 c) {
  return __builtin_amdgcn_mfma_f32_16x16x32_bf16(
      __builtin_bit_cast(bf16x8, a), __builtin_bit_cast(bf16x8, b), c, 0, 0, 0);
}

__device__ __forceinline__ void make_M(float A, float st,
    float& m11, float& m12, float& m21, float& m22) {
  float s2A   = st * st * A;
  float schur = 1.0f / (1.0f + s2A);
  m11 = 1.0f - s2A * schur;
  m12 = -st * A * schur;
  m21 = st * schur;
  m22 = schur;
}

// ------------------------------------------------- prep: weights -> bf16, output-major
__global__ __launch_bounds__(256) void prep_kernel(
    const float* __restrict__ Br, const float* __restrict__ Bi,
    const float* __restrict__ Cr, const float* __restrict__ Ci,
    unsigned short* __restrict__ WbN, unsigned short* __restrict__ WcH) {
  int tid = blockIdx.x * 256 + threadIdx.x;
  if (tid < Hn * Kn) {
    int n = tid >> 7, h = tid & 127, p = n >> 1;
    float v = (n & 1) ? Bi[p * Hn + h] : Br[p * Hn + h];
    WbN[tid] = f2bf(v);
  } else {
    int i = tid - Hn * Kn;
    int h = i >> 7, k = i & 127, p = k >> 1;
    float v = (k & 1) ? -Ci[h * Pn + p] : Cr[h * Pn + p];
    WcH[i] = f2bf(v);
  }
}

// ------------------------------------------------- shared device phase bodies (round-4 proven)
// 64x128 @ 128x128 MFMA tile; usb swizzled bf16 A-tile; W [128 out][128 k]
__device__ __forceinline__ void gemm_tile(
    const unsigned short* __restrict__ usb,
    const unsigned short* __restrict__ W,
    float* __restrict__ outlds, int t) {
  const int wave = t >> 6, lane = t & 63;
  const int arow = wave * 16 + (lane & 15);
  const int kg = lane >> 4;                  // k = kk*32 + kg*8 + j

  us8 afr[4];
  #pragma unroll
  for (int kk = 0; kk < 4; ++kk)
    afr[kk] = *(const us8*)((const char*)usb +
        ((arow * 256 + kk * 64 + kg * 16) ^ ((arow & 7) << 4)));

  #pragma unroll
  for (int nt = 0; nt < 8; ++nt) {
    const int n = nt * 16 + (lane & 15);
    f32x4 acc = {0.f, 0.f, 0.f, 0.f};
    #pragma unroll
    for (int kk = 0; kk < 4; ++kk) {
      us8 bfr = *(const us8*)(W + n * Kn + kk * 32 + kg * 8);
      acc = mfma_bf16(afr[kk], bfr, acc);
    }
    const int crow = wave * 16 + (lane >> 4) * 4;
    const int ccol = nt * 16 + (lane & 15);
    #pragma unroll
    for (int r = 0; r < 4; ++r)
      outlds[(crow + r) * Kn + ccol] = acc[r];
  }
}

__device__ __forceinline__ void stage_u_tile(
    const f4* __restrict__ u4, unsigned short* usb, f4* ureg, int t) {
  #pragma unroll
  for (int i = 0; i < 8; ++i) {
    int idx = t + i * 256;
    f4 v = u4[idx];
    ureg[i] = v;
    int row = idx >> 5, c0 = (idx & 31) * 4;
    us4 pk = {f2bf(v[0]), f2bf(v[1]), f2bf(v[2]), f2bf(v[3])};
    *(us4*)((char*)usb + ((row * 256 + c0 * 2) ^ ((row & 7) << 4))) = pk;
  }
}

__device__ __forceinline__ void chunk_scan(
    const float* bu, const float* __restrict__ Ad, const float* __restrict__ steps,
    float2* __restrict__ carry, int t, int b, int chunk) {
  if (t < Kn) {
    const int p = t >> 1;
    const float A  = fmaxf(Ad[p], 0.0f);
    const float st = 1.0f / (1.0f + expf(-steps[p]));
    float m11, m12, m21, m22;
    make_M(A, st, m11, m12, m21, m22);
    const float f1 = m11 * st, f2 = m21 * st;
    float z = 0.f, x = 0.f;
    #pragma unroll 8
    for (int s = 0; s < Sc; ++s) {
      float bv = bu[s * Kn + t];
      float zn = fmaf(m11, z, fmaf(m12, x, f1 * bv));
      float xn = fmaf(m21, z, fmaf(m22, x, f2 * bv));
      z = zn; x = xn;
    }
    carry[((size_t)b * NC + chunk) * Kn + t] = make_float2(z, x);
  }
}

__device__ __forceinline__ void chunk_rescan(
    float* bu, const float* __restrict__ Ad, const float* __restrict__ steps,
    const float2* __restrict__ carry, int t, int b, int chunk) {
  if (t < Kn) {
    const int p = t >> 1;
    const float A  = fmaxf(Ad[p], 0.0f);
    const float st = 1.0f / (1.0f + expf(-steps[p]));
    float m11, m12, m21, m22;
    make_M(A, st, m11, m12, m21, m22);
    const float f1 = m11 * st, f2 = m21 * st;
    float2 init = carry[((size_t)b * NC + chunk) * Kn + t];
    float z = init.x, x = init.y;
    #pragma unroll 8
    for (int s = 0; s < Sc; ++s) {
      float bv = bu[s * Kn + t];
      float zn = fmaf(m11, z, fmaf(m12, x, f1 * bv));
      float xn = fmaf(m21, z, fmaf(m22, x, f2 * bv));
      z = zn; x = xn;
      bu[s * Kn + t] = x;
    }
  }
}

// wave-parallel carry propagation; blk in [0, Bn*Kn/4)
__device__ __forceinline__ void propagate_body(
    const float* __restrict__ Ad, const float* __restrict__ steps,
    float2* __restrict__ carry, int t, int blk) {
  const int wave = t >> 6, lane = t & 63;
  const int series = blk * 4 + wave;          // 0..511
  const int sb = series >> 7;
  const int k = series & 127;
  const int p = k >> 1;

  const float A  = fmaxf(Ad[p], 0.0f);
  const float st = 1.0f / (1.0f + expf(-steps[p]));
  float m11, m12, m21, m22;
  make_M(A, st, m11, m12, m21, m22);
  // Mc = M^Sc (Sc=64 -> 6 squarings)
  float ca = m11, cb = m12, cc = m21, cd = m22;
  #pragma unroll
  for (int i = 0; i < 6; ++i) {
    float na = ca * ca + cb * cc;
    float nb = ca * cb + cb * cd;
    float nc = cc * ca + cd * cc;
    float nd = cc * cb + cd * cd;
    ca = na; cb = nb; cc = nc; cd = nd;
  }

  const size_t base = (size_t)sb * NC * Kn + k;
  float2 c0 = carry[base + (size_t)(2 * lane) * Kn];
  float2 c1 = carry[base + (size_t)(2 * lane + 1) * Kn];

  // lane-local fold of chunks {2i, 2i+1}
  float Aa = ca * ca + cb * cc;
  float Ab = ca * cb + cb * cd;
  float Ac = cc * ca + cd * cc;
  float Adl = cc * cb + cd * cd;
  float bz = ca * c0.x + cb * c0.y + c1.x;
  float bx = cc * c0.x + cd * c0.y + c1.y;

  // inclusive shfl-scan of affine maps
  #pragma unroll
  for (int d = 1; d < 64; d <<= 1) {
    float oAa = __shfl_up(Aa, d), oAb = __shfl_up(Ab, d);
    float oAc = __shfl_up(Ac, d), oAd = __shfl_up(Adl, d);
    float obz = __shfl_up(bz, d), obx = __shfl_up(bx, d);
    if (lane >= d) {
      float nbz = Aa * obz + Ab * obx + bz;
      float nbx = Ac * obz + Adl * obx + bx;
      float nAa = Aa * oAa + Ab * oAc;
      float nAb = Aa * oAb + Ab * oAd;
      float nAc = Ac * oAa + Adl * oAc;
      float nAd = Ac * oAb + Adl * oAd;
      Aa = nAa; Ab = nAb; Ac = nAc; Adl = nAd; bz = nbz; bx = nbx;
    }
  }

  // exclusive prefix; init for chunk 2i, then 2i+1 = Mc*init + c0
  float ebz = __shfl_up(bz, 1);
  float ebx = __shfl_up(bx, 1);
  if (lane == 0) { ebz = 0.f; ebx = 0.f; }

  carry[base + (size_t)(2 * lane) * Kn]     = make_float2(ebz, ebx);
  carry[base + (size_t)(2 * lane + 1) * Kn] =
      make_float2(ca * ebz + cb * ebx + c0.x, cc * ebz + cd * ebx + c0.y);
}

__device__ __forceinline__ void ys_to_bf16(
    const float* bu, unsigned short* usb, int t) {
  #pragma unroll
  for (int i = 0; i < 8; ++i) {
    int idx = t + i * 256;
    int row = idx >> 5, c0 = (idx & 31) * 4;
    f4 v = *(const f4*)&bu[row * Kn + c0];
    us4 pk = {f2bf(v[0]), f2bf(v[1]), f2bf(v[2]), f2bf(v[3])};
    *(us4*)((char*)usb + ((row * 256 + c0 * 2) ^ ((row & 7) << 4))) = pk;
  }
}

__device__ __forceinline__ void out_epilogue(
    const float* bu, const f4* ureg, const float* __restrict__ Dv,
    float* __restrict__ out, size_t row0, int t) {
  const f4* __restrict__ Dv4 = (const f4*)Dv;
  f4* __restrict__ out4 = (f4*)out;
  #pragma unroll
  for (int i = 0; i < 8; ++i) {
    int idx = t + i * 256;
    int row = idx >> 5, c0 = (idx & 31) * 4;
    f4 acc = *(const f4*)&bu[row * Kn + c0];
    f4 dv = Dv4[idx & 31];
    f4 res;
    #pragma unroll
    for (int j = 0; j < 4; ++j) res[j] = fmaf(ureg[i][j], dv[j], acc[j]);
    out4[row0 * (Hn / 4) + idx] = res;
  }
}

// ------------------------------------------------- fused cooperative kernel
__global__ __launch_bounds__(256, 3) void fused_kernel(
    const float* __restrict__ u, const unsigned short* __restrict__ WbN,
    const unsigned short* __restrict__ WcH, const float* __restrict__ Dv,
    const float* __restrict__ Ad, const float* __restrict__ steps,
    float2* __restrict__ carry, float* __restrict__ out) {
  __shared__ unsigned short usb[Sc * Hn];   // 16 KB
  __shared__ float bu[Sc * Kn];             // 32 KB
  const int t = threadIdx.x;
  const int b = blockIdx.x >> 7;            // NC = 128
  const int chunk = blockIdx.x & (NC - 1);
  const size_t row0 = (size_t)b * Ln + (size_t)chunk * Sc;

  f4 ureg[8];
  stage_u_tile((const f4*)(u + row0 * Hn), usb, ureg, t);
  __syncthreads();
  gemm_tile(usb, WbN, bu, t);
  __syncthreads();
  chunk_scan(bu, Ad, steps, carry, t, b, chunk);

  cg::this_grid().sync();
  if (blockIdx.x < Bn * Kn / 4) propagate_body(Ad, steps, carry, t, blockIdx.x);
  cg::this_grid().sync();

  chunk_rescan(bu, Ad, steps, carry, t, b, chunk);
  __syncthreads();
  ys_to_bf16(bu, usb, t);
  __syncthreads();
  gemm_tile(usb, WcH, bu, t);
  __syncthreads();
  out_epilogue(bu, ureg, Dv, out, row0, t);
}

// ------------------------------------------------- fallback split kernels (round-4 structure)
__global__ __launch_bounds__(256) void k1_bu_scan(
    const float* __restrict__ u, const unsigned short* __restrict__ WbN,
    const float* __restrict__ Ad, const float* __restrict__ steps,
    float2* __restrict__ carry) {
  __shared__ unsigned short usb[Sc * Hn];
  __shared__ float bu[Sc * Kn];
  const int t = threadIdx.x;
  const int b = blockIdx.x >> 7;
  const int chunk = blockIdx.x & (NC - 1);
  const size_t row0 = (size_t)b * Ln + (size_t)chunk * Sc;

  f4 ureg[8];
  stage_u_tile((const f4*)(u + row0 * Hn), usb, ureg, t);
  __syncthreads();
  gemm_tile(usb, WbN, bu, t);
  __syncthreads();
  chunk_scan(bu, Ad, steps, carry, t, b, chunk);
}

__global__ __launch_bounds__(256) void k2_propagate(
    const float* __restrict__ Ad, const float* __restrict__ steps,
    float2* __restrict__ carry) {
  propagate_body(Ad, steps, carry, threadIdx.x, blockIdx.x);
}

__global__ __launch_bounds__(256) void k3_scan_out(
    const float* __restrict__ u, const unsigned short* __restrict__ WbN,
    const unsigned short* __restrict__ WcH, const float* __restrict__ Dv,
    const float* __restrict__ Ad, const float* __restrict__ steps,
    const float2* __restrict__ carry, float* __restrict__ out) {
  __shared__ unsigned short usb[Sc * Hn];
  __shared__ float bu[Sc * Kn];
  const int t = threadIdx.x;
  const int b = blockIdx.x >> 7;
  const int chunk = blockIdx.x & (NC - 1);
  const size_t row0 = (size_t)b * Ln + (size_t)chunk * Sc;

  f4 ureg[8];
  stage_u_tile((const f4*)(u + row0 * Hn), usb, ureg, t);
  __syncthreads();
  gemm_tile(usb, WbN, bu, t);
  __syncthreads();
  chunk_rescan(bu, Ad, steps, carry, t, b, chunk);
  __syncthreads();
  ys_to_bf16(bu, usb, t);
  __syncthreads();
  gemm_tile(usb, WcH, bu, t);
  __syncthreads();
  out_epilogue(bu, ureg, Dv, out, row0, t);
}

extern "C" void kernel_launch(void* const* d_in, const int* in_sizes, int n_in,
                              void* d_out, int out_size, void* d_ws, size_t ws_size,
                              hipStream_t stream) {
  const float* u     = (const float*)d_in[0];
  const float* Ad    = (const float*)d_in[1];
  const float* Br    = (const float*)d_in[2];
  const float* Bi    = (const float*)d_in[3];
  const float* Cr    = (const float*)d_in[4];
  const float* Ci    = (const float*)d_in[5];
  const float* Dv    = (const float*)d_in[6];
  const float* steps = (const float*)d_in[7];
  float* out = (float*)d_out;

  // workspace: carry [B*NC*Kn float2 = 512KB] | WbN bf16 [32KB] | WcH bf16 [32KB]
  float2* carry = (float2*)d_ws;
  unsigned short* WbN = (unsigned short*)(carry + (size_t)Bn * NC * Kn);
  unsigned short* WcH = WbN + Hn * Kn;

  prep_kernel<<<2 * Hn * Kn / 256, 256, 0, stream>>>(Br, Bi, Cr, Ci, WbN, WcH);

  // host-side, capture-safe, deterministic occupancy gate for cooperative launch
  int maxB = 0;
  (void)hipOccupancyMaxActiveBlocksPerMultiprocessor(&maxB, fused_kernel, 256, 0);
  int dev = 0, nCU = 0;
  (void)hipGetDevice(&dev);
  (void)hipDeviceGetAttribute(&nCU, hipDeviceAttributeMultiprocessorCount, dev);

  hipError_t e = hipErrorUnknown;
  if ((long)maxB * nCU >= NBLK) {
    void* args[8] = {(void*)&u, (void*)&WbN, (void*)&WcH, (void*)&Dv,
                     (void*)&Ad, (void*)&steps, (void*)&carry, (void*)&out};
    e = hipLaunchCooperativeKernel(fused_kernel, dim3(NBLK), dim3(256), args, 0, stream);
  }
  if (e != hipSuccess) {
    k1_bu_scan  <<<NBLK,          256, 0, stream>>>(u, WbN, Ad, steps, carry);
    k2_propagate<<<Bn * Kn / 4,   256, 0, stream>>>(Ad, steps, carry);
    k3_scan_out <<<NBLK,          256, 0, stream>>>(u, WbN, WcH, Dv, Ad, steps, carry, out);
  }
}